// Round 6
// baseline (128.581 us; speedup 1.0000x reference)
//
#include <hip/hip_runtime.h>
#include <stdint.h>

// B=8, S=4096, D=64 dense attention + 3 fused 64x64 linear projections.
// proj_kernel: Qb (bf16, pre-scaled log2e/8), Kb (bf16 row-major),
//              Vt (bf16, [b][d][s]; within each 64-key block, key index has
//              bits 2<->3 swapped so PV's B-operand is lane-local).
// attn_kernel: flash attn, 32x32x16 bf16 MFMA, q=64/wave, 4-way KV-split,
//              per-wave private staging (NO in-loop barriers; vmcnt/lgkmcnt
//              fences), base-2 online softmax with defer-max, in-register P,
//              two-phase LDS merge of the 4 per-wave partials.

#define B_ 8
#define S_ 4096
#define D_ 64
#define THR 7.0f

typedef short bf16x8 __attribute__((ext_vector_type(8)));
typedef float f32x4 __attribute__((ext_vector_type(4)));
typedef float f32x16 __attribute__((ext_vector_type(16)));

#define MFMA16(a, b, c) __builtin_amdgcn_mfma_f32_16x16x32_bf16((a), (b), (c), 0, 0, 0)
#define MFMA32(a, b, c) __builtin_amdgcn_mfma_f32_32x32x16_bf16((a), (b), (c), 0, 0, 0)

static __device__ __forceinline__ unsigned short f2bf(float x) {
  union { float f; unsigned u; } v; v.f = x;
  unsigned r = v.u + 0x7FFFu + ((v.u >> 16) & 1u);   // RNE
  return (unsigned short)(r >> 16);
}
static __device__ __forceinline__ void gload16(const void* g, void* l) {
  __builtin_amdgcn_global_load_lds(
      (const __attribute__((address_space(1))) unsigned int*)g,
      (__attribute__((address_space(3))) unsigned int*)l, 16, 0, 0);
}

union U8 { unsigned short s[8]; uint4 v; };
union PB { int w[4]; bf16x8 v; };

// ---------------------------------------------------------------------------
// Projection kernel. grid 512 (8 batches x 64 row-tiles), block 256.
// ---------------------------------------------------------------------------
__global__ __launch_bounds__(256) void proj_kernel(
    const float* __restrict__ x,
    const float* __restrict__ Wq, const float* __restrict__ bq,
    const float* __restrict__ Wk, const float* __restrict__ bk,
    const float* __restrict__ Wv, const float* __restrict__ bv,
    unsigned short* __restrict__ Qb, unsigned short* __restrict__ Kb,
    unsigned short* __restrict__ Vt) {
  __shared__ unsigned short xb[64 * 64];      // swizzled; reused for Q bounce
  __shared__ unsigned short wb[3][64 * 64];   // swizzled; wb[0] reused for K bounce
  __shared__ unsigned short vtmp[64 * 64];    // LINEAR [s][e] for V transpose

  const int tid = threadIdx.x;
  const int blk = blockIdx.x;
  const int batch = blk >> 6;
  const int s0 = (blk & 63) << 6;

  const int row = tid >> 2, c0 = (tid & 3) << 4;
  const int sw = (row & 7) << 4;

  // ---- stage x tile (float4 loads -> bf16, swizzled) ----
  {
    const float4* src = (const float4*)(x + ((size_t)(batch * S_ + s0 + row)) * D_ + c0);
    float4 f[4];
#pragma unroll
    for (int i = 0; i < 4; i++) f[i] = src[i];
    const float* ff = (const float*)f;
    U8 a, b;
#pragma unroll
    for (int i = 0; i < 8; i++) a.s[i] = f2bf(ff[i]);
#pragma unroll
    for (int i = 0; i < 8; i++) b.s[i] = f2bf(ff[8 + i]);
    char* lp = (char*)xb + row * 128;
    *(uint4*)(lp + ((c0 * 2) ^ sw)) = a.v;
    *(uint4*)(lp + ((c0 * 2 + 16) ^ sw)) = b.v;
  }
  // ---- stage W matrices (float4 loads -> bf16, swizzled) ----
  {
    const float* Ws[3] = {Wq, Wk, Wv};
#pragma unroll
    for (int m = 0; m < 3; m++) {
      const float4* src = (const float4*)(Ws[m] + row * 64 + c0);
      float4 f[4];
#pragma unroll
      for (int i = 0; i < 4; i++) f[i] = src[i];
      const float* ff = (const float*)f;
      U8 a, b;
#pragma unroll
      for (int i = 0; i < 8; i++) a.s[i] = f2bf(ff[i]);
#pragma unroll
      for (int i = 0; i < 8; i++) b.s[i] = f2bf(ff[8 + i]);
      char* lp = (char*)wb[m] + row * 128;
      *(uint4*)(lp + ((c0 * 2) ^ sw)) = a.v;
      *(uint4*)(lp + ((c0 * 2 + 16) ^ sw)) = b.v;
    }
  }
  __syncthreads();

  const int lane = tid & 63;
  const int w = tid >> 6;
  const int g = lane >> 4;
  const int lr = lane & 15;

  bf16x8 xa0, xa1;
  {
    const int xr = w * 16 + lr;
    const int swz = (xr & 7) << 4;
    const char* lp = (const char*)xb + xr * 128;
    xa0 = *(const bf16x8*)(lp + ((g * 16) ^ swz));
    xa1 = *(const bf16x8*)(lp + ((64 + g * 16) ^ swz));
  }

  f32x4 acc[3][4];
#pragma unroll
  for (int m = 0; m < 3; m++)
#pragma unroll
    for (int n = 0; n < 4; n++) { acc[m][n][0] = 0.f; acc[m][n][1] = 0.f; acc[m][n][2] = 0.f; acc[m][n][3] = 0.f; }
#pragma unroll
  for (int m = 0; m < 3; m++) {
#pragma unroll
    for (int n = 0; n < 4; n++) {
      const int erow = n * 16 + lr;
      const int swz = (erow & 7) << 4;
      const char* lp = (const char*)wb[m] + erow * 128;
      bf16x8 w0 = *(const bf16x8*)(lp + ((g * 16) ^ swz));
      bf16x8 w1 = *(const bf16x8*)(lp + ((64 + g * 16) ^ swz));
      acc[m][n] = MFMA16(xa0, w0, acc[m][n]);
      acc[m][n] = MFMA16(xa1, w1, acc[m][n]);
    }
  }
  __syncthreads();   // all fragment reads done -> xb / wb[0] / vtmp reusable

  // ---- bounce: Q -> xb (swizzled), K -> wb[0] (swizzled), V -> vtmp (linear) ----
  // D layout: row(s-local) = w*16 + 4*g + reg, col(e) = 16*n + lr
  {
#pragma unroll
    for (int n = 0; n < 4; n++) {
      const float bq_ = bq[n * 16 + lr];
      const float bk_ = bk[n * 16 + lr];
      const float bv_ = bv[n * 16 + lr];
#pragma unroll
      for (int r = 0; r < 4; r++) {
        const int orow = w * 16 + 4 * g + r;
        const int cb = ((n * 16 + lr) * 2) ^ ((orow & 7) << 4);
        *(unsigned short*)((char*)xb + orow * 128 + cb) =
            f2bf((acc[0][n][r] + bq_) * 0.18033688011112042f);   // (1/8)*log2(e) into Q
        *(unsigned short*)((char*)wb[0] + orow * 128 + cb) = f2bf(acc[1][n][r] + bk_);
        vtmp[orow * 64 + n * 16 + lr] = f2bf(acc[2][n][r] + bv_);
      }
    }
  }
  __syncthreads();

  // ---- coalesced wide stores ----
  {
    const char* qs_ = (const char*)xb + row * 128;
    uint4 q0 = *(const uint4*)(qs_ + ((c0 * 2) ^ sw));
    uint4 q1 = *(const uint4*)(qs_ + ((c0 * 2 + 16) ^ sw));
    unsigned short* qd = Qb + ((size_t)batch * S_ + s0 + row) * D_ + c0;
    *(uint4*)qd = q0;
    *(uint4*)(qd + 8) = q1;

    const char* ks_ = (const char*)wb[0] + row * 128;
    uint4 k0 = *(const uint4*)(ks_ + ((c0 * 2) ^ sw));
    uint4 k1 = *(const uint4*)(ks_ + ((c0 * 2 + 16) ^ sw));
    unsigned short* kd = Kb + ((size_t)batch * S_ + s0 + row) * D_ + c0;
    *(uint4*)kd = k0;
    *(uint4*)(kd + 8) = k1;

    // Vt[b][e][blk64 + p] = V[blk64 + pi(p)][e];  pi = swap bits 2<->3 of p
    const int e = row, sc0 = c0;
    union { unsigned short s[16]; uint4 v[2]; } o;
#pragma unroll
    for (int i = 0; i < 16; i++) {
      const int kap = sc0 + ((i & 3) | ((i & 4) << 1) | ((i & 8) >> 1));
      o.s[i] = vtmp[kap * 64 + e];
    }
    uint4* dst = (uint4*)(Vt + (size_t)batch * (64 * S_) + (size_t)e * S_ + s0 + sc0);
    dst[0] = o.v[0];
    dst[1] = o.v[1];
  }
}

// ---------------------------------------------------------------------------
// Flash attention. grid 512 (batch = bid&7 for XCD/L2 locality), block 256.
// Wave w owns KV tiles [w*16, w*16+16) x all 64 q rows of the block.
// Per-wave private 16KB staging buffer; no barriers in the main loop.
// ---------------------------------------------------------------------------
__global__ __launch_bounds__(256, 2) void attn_kernel(
    const unsigned short* __restrict__ Qb, const unsigned short* __restrict__ Kb,
    const unsigned short* __restrict__ Vt, float* __restrict__ out) {
  __shared__ char lds[65536];   // 4 waves x (K 8KB | V 8KB); reused for merge

  const int bid = blockIdx.x;
  const int batch = bid & 7;
  const int qblk = bid >> 3;
  const int tid = threadIdx.x;
  const int lane = tid & 63;
  const int w = tid >> 6;
  const int q32 = lane & 31;
  const int hi = lane >> 5;
  const int swz = (q32 & 7) << 4;

  const size_t bOff = (size_t)batch * S_ * D_;
  char* const wbase = lds + (w << 14);

  // Q B-fragments: qa[qb][c] = Q[qblk*64 + qb*32 + q32][16c + 8hi + j]
  bf16x8 qa[2][4];
#pragma unroll
  for (int qb = 0; qb < 2; qb++) {
    const unsigned short* qp = Qb + bOff + (size_t)(qblk * 64 + qb * 32 + q32) * D_ + hi * 8;
#pragma unroll
    for (int c = 0; c < 4; c++) qa[qb][c] = *(const bf16x8*)(qp + c * 16);
  }

  f32x16 oacc[2][2];
#pragma unroll
  for (int qb = 0; qb < 2; qb++)
#pragma unroll
    for (int n = 0; n < 2; n++)
#pragma unroll
      for (int i = 0; i < 16; i++) oacc[qb][n][i] = 0.f;
  float m_[2] = {-__builtin_inff(), -__builtin_inff()};
  float l_[2] = {0.f, 0.f};

  // ---- staging geometry (wave-private tile) ----
  const int rsub = lane >> 3;
  const int csw = ((lane & 7) ^ rsub) << 4;
  const char* ksrc0 = (const char*)(Kb + bOff) + rsub * 128 + csw;    // + kt*8192 + c*1024
  const char* vsrc0 = (const char*)(Vt + bOff) + rsub * 8192 + csw;   // + kt*128  + c*65536
  char* const kdst = wbase + lane * 16;
  char* const vdst = wbase + 8192 + lane * 16;

  auto STAGE = [&](int kt) {
    const char* ks = ksrc0 + (size_t)kt * 8192;
    const char* vs = vsrc0 + (size_t)kt * 128;
#pragma unroll
    for (int c = 0; c < 8; c++) {
      gload16(ks + c * 1024, kdst + c * 1024);
      gload16(vs + c * 65536, vdst + c * 1024);
    }
  };

  STAGE(w * 16);

  for (int t = 0; t < 16; t++) {
    asm volatile("s_waitcnt vmcnt(0)" ::: "memory");   // tile staged (wave-private)

    // ---- fragment ds_reads (whole tile into regs) ----
    bf16x8 ka[2][4], va[2][4];
#pragma unroll
    for (int m = 0; m < 2; m++) {
      const char* kp = wbase + (m * 32 + q32) * 128;
#pragma unroll
      for (int c = 0; c < 4; c++)
        ka[m][c] = *(const bf16x8*)(kp + ((c * 32 + hi * 16) ^ swz));
    }
#pragma unroll
    for (int n = 0; n < 2; n++) {
      const char* vp = wbase + 8192 + (n * 32 + q32) * 128;
#pragma unroll
      for (int s = 0; s < 4; s++)
        va[n][s] = *(const bf16x8*)(vp + ((s * 32 + hi * 16) ^ swz));
    }

    asm volatile("s_waitcnt lgkmcnt(0)" ::: "memory"); // reads done -> buffer reusable
    if (t < 15) STAGE(w * 16 + t + 1);                 // prefetch hides under compute

#pragma unroll
    for (int qb = 0; qb < 2; qb++) {
      // ---- QK^T (swapped: A=K rows, B=Q): lane holds S^T[k][q=q32] ----
      f32x16 sa[2];
#pragma unroll
      for (int m = 0; m < 2; m++) {
#pragma unroll
        for (int i = 0; i < 16; i++) sa[m][i] = 0.f;
      }
      __builtin_amdgcn_s_setprio(1);
#pragma unroll
      for (int m = 0; m < 2; m++)
#pragma unroll
        for (int c = 0; c < 4; c++) sa[m] = MFMA32(ka[m][c], qa[qb][c], sa[m]);
      __builtin_amdgcn_s_setprio(0);

      // ---- online softmax (base-2), defer-max; partner lane = lane^32 ----
      float tm[16];
#pragma unroll
      for (int i = 0; i < 16; i++) tm[i] = fmaxf(sa[0][i], sa[1][i]);
#pragma unroll
      for (int i = 0; i < 8; i++) tm[i] = fmaxf(tm[i], tm[i + 8]);
#pragma unroll
      for (int i = 0; i < 4; i++) tm[i] = fmaxf(tm[i], tm[i + 4]);
      const float lmax = fmaxf(fmaxf(tm[0], tm[1]), fmaxf(tm[2], tm[3]));
      if (!__all(lmax <= m_[qb] + THR)) {
        const float mx = fmaxf(lmax, __shfl_xor(lmax, 32));
        const float mn = fmaxf(m_[qb], mx);
        const float fac = __builtin_amdgcn_exp2f(m_[qb] - mn);
        m_[qb] = mn;
        l_[qb] *= fac;
        oacc[qb][0] *= fac;
        oacc[qb][1] *= fac;
      }
#pragma unroll
      for (int m = 0; m < 2; m++)
#pragma unroll
        for (int i = 0; i < 16; i++) sa[m][i] = __builtin_amdgcn_exp2f(sa[m][i] - m_[qb]);
      float ts[16];
#pragma unroll
      for (int i = 0; i < 16; i++) ts[i] = sa[0][i] + sa[1][i];
#pragma unroll
      for (int i = 0; i < 8; i++) ts[i] += ts[i + 8];
#pragma unroll
      for (int i = 0; i < 4; i++) ts[i] += ts[i + 4];
      l_[qb] += (ts[0] + ts[1]) + (ts[2] + ts[3]);

      // ---- P -> bf16 fragments (lane-local; V column order pre-permuted) ----
      PB pbs[4];
#pragma unroll
      for (int s = 0; s < 4; s++) {
        const int m = s >> 1, h = (s & 1) * 8;
#pragma unroll
        for (int i = 0; i < 4; i++) {
          int r_;
          asm("v_cvt_pk_bf16_f32 %0, %1, %2"
              : "=v"(r_) : "v"(sa[m][h + 2 * i]), "v"(sa[m][h + 2 * i + 1]));
          pbs[s].w[i] = r_;
        }
      }

      // ---- PV (swapped: A=V^T rows, B=P^T): O^T[d][q=q32] ----
      __builtin_amdgcn_s_setprio(1);
#pragma unroll
      for (int n = 0; n < 2; n++)
#pragma unroll
        for (int s = 0; s < 4; s++) oacc[qb][n] = MFMA32(va[n][s], pbs[s].v, oacc[qb][n]);
      __builtin_amdgcn_s_setprio(0);
    }
  }

  // ---- pair-reduce l (k-halves live on lane and lane^32) ----
#pragma unroll
  for (int qb = 0; qb < 2; qb++) l_[qb] += __shfl_xor(l_[qb], 32);

  __syncthreads();   // all waves done with staging LDS

  // ---- two-phase merge of the 4 per-wave partials ----
#pragma unroll
  for (int ph = 0; ph < 2; ph++) {
    // write O partial: [w][q(0..31)][d(0..63)] fp32, 16B chunks XOR-swizzled by q
    {
      char* ob = lds + w * 8192 + q32 * 256;
#pragma unroll
      for (int n = 0; n < 2; n++)
#pragma unroll
        for (int u = 0; u < 4; u++) {
          f32x4 vv;
          vv[0] = oacc[ph][n][4 * u + 0];
          vv[1] = oacc[ph][n][4 * u + 1];
          vv[2] = oacc[ph][n][4 * u + 2];
          vv[3] = oacc[ph][n][4 * u + 3];
          const int chunk = 2 * u + hi + 8 * n;    // d = 4*chunk .. +4
          *(f32x4*)(ob + ((chunk * 16) ^ swz)) = vv;
        }
      if (hi == 0) {
        float2 ml; ml.x = m_[ph]; ml.y = l_[ph];
        *(float2*)(lds + 32768 + w * 256 + q32 * 8) = ml;
      }
    }
    __syncthreads();
    // merge: wave w handles q in [w*8, w*8+8); lane: q = w*8 + (lane>>3), d0 = (lane&7)*8
    {
      const int q = w * 8 + (lane >> 3);
      const int dc = (lane & 7) * 2;
      const int qsw = (q & 7) << 4;
      float2 ml[4];
#pragma unroll
      for (int w4 = 0; w4 < 4; w4++) ml[w4] = *(const float2*)(lds + 32768 + w4 * 256 + q * 8);
      const float M = fmaxf(fmaxf(ml[0].x, ml[1].x), fmaxf(ml[2].x, ml[3].x));
      float a[4], L = 0.f;
#pragma unroll
      for (int w4 = 0; w4 < 4; w4++) { a[w4] = __builtin_amdgcn_exp2f(ml[w4].x - M); L += a[w4] * ml[w4].y; }
      f32x4 o0, o1;
      o0[0] = o0[1] = o0[2] = o0[3] = 0.f;
      o1[0] = o1[1] = o1[2] = o1[3] = 0.f;
#pragma unroll
      for (int w4 = 0; w4 < 4; w4++) {
        const char* pb_ = lds + w4 * 8192 + q * 256;
        f32x4 r0 = *(const f32x4*)(pb_ + ((dc * 16) ^ qsw));
        f32x4 r1 = *(const f32x4*)(pb_ + (((dc + 1) * 16) ^ qsw));
        o0 += r0 * a[w4];
        o1 += r1 * a[w4];
      }
      const float inv = 1.0f / L;
      float* orow = out + ((size_t)batch * S_ + qblk * 64 + ph * 32 + q) * D_ + (lane & 7) * 8;
      *(f32x4*)orow = o0 * inv;
      *(f32x4*)(orow + 4) = o1 * inv;
    }
    __syncthreads();   // before phase-1 overwrites the merge buffer
  }
}

// ---------------------------------------------------------------------------
extern "C" void kernel_launch(void* const* d_in, const int* in_sizes, int n_in,
                              void* d_out, int out_size, void* d_ws, size_t ws_size,
                              hipStream_t stream) {
  const float* x  = (const float*)d_in[0];
  const float* Wq = (const float*)d_in[1];
  const float* bq = (const float*)d_in[2];
  const float* Wk = (const float*)d_in[3];
  const float* bk = (const float*)d_in[4];
  const float* Wv = (const float*)d_in[5];
  const float* bv = (const float*)d_in[6];

  unsigned short* Qb = (unsigned short*)d_ws;            // bf16, pre-scaled log2e/8
  unsigned short* Kb = Qb + (size_t)B_ * S_ * D_;        // bf16 row-major
  unsigned short* Vt = Kb + (size_t)B_ * S_ * D_;        // bf16 [b][d][s], bit2<->3-permuted

  proj_kernel<<<512, 256, 0, stream>>>(x, Wq, bq, Wk, bk, Wv, bv, Qb, Kb, Vt);
  attn_kernel<<<512, 256, 0, stream>>>(Qb, Kb, Vt, (float*)d_out);
}